// Round 4
// baseline (109.593 us; speedup 1.0000x reference)
//
#include <hip/hip_runtime.h>
#include <hip/hip_bf16.h>

// IGD metric kernel for MI355X (gfx950).
// d2(i,j) = pfsq[i] + [xsq_j + dot(-2*pf_i, x_j)], the bracket computed entirely in one MFMA
// chain: K extended 64->80, B fragment 4 = [bf16_hi(xsq), bf16_lo(xsq), 0...], A fragment 4 =
// [1,1,0,...] (constant, no load). norms from rounded values -> consistent sq-distances.
// R4: K-80 xsq fold (removes 32 v_add + 1 load per unit; per-unit pipe now MFMA 80cyc vs
// VALU ~70cyc), persistent zero-C (no per-unit acc zeroing). Structure else per R3:
// fragment-linear packed B (dense 1KB wave loads), 3 blocks/CU, 12 ragged splits, ping-pong.
// NOTE: harness re-poison fill of the 256MB workspace (~42us @ 6.4TB/s) is inside the timed
// window every round -- fixed overhead; our controllable part is dur_us - 42.

typedef __bf16 bf16x8 __attribute__((ext_vector_type(8)));
typedef float f32x16 __attribute__((ext_vector_type(16)));

#define DIM 64
#define KF 5          // 4 data fragments + 1 xsq fragment
#define USTRIDE (KF * 64 * 8)   // 2560 elems per 32-col unit
#define NSPLIT 12
#define MTILE 256     // rows per block (4 waves x 64 rows)

// ---------------- pack ----------------
// x -> Bp fragment-linear: unit u (32 cols), frag t in [0,5), lane = half*32 + (col&31):
//   t<4:  Bp[((u*5+t)*64 + half*32 + c31)*8 + j] = bf16(x[col][t*16 + half*8 + j])
//   t==4: half0: {bf16_hi(xsq[col]), bf16_lo(residual), 0...}; half1: zeros
// pf -> Ab row-major bf16(-2*pf); pfsq = 0.25 * sum(bf16(-2*pf)^2).
__global__ void pack_kernel(const float* __restrict__ x, const float* __restrict__ pf,
                            __bf16* __restrict__ Bp, __bf16* __restrict__ Ab,
                            float* __restrict__ pfsq, float* __restrict__ out, int N, int M) {
    int gid = blockIdx.x * blockDim.x + threadIdx.x;
    if (gid == 0) out[0] = 0.f;
    if (gid < N * 4) {
        int col = gid >> 2, t = gid & 3;
        const float* s = x + (size_t)col * DIM + t * 16;
        float partial = 0.f;
        bf16x8 outv[2];
#pragma unroll
        for (int h = 0; h < 2; ++h) {
            float4 v0 = *(const float4*)(s + h * 8);
            float4 v1 = *(const float4*)(s + h * 8 + 4);
            float f[8] = {v0.x, v0.y, v0.z, v0.w, v1.x, v1.y, v1.z, v1.w};
#pragma unroll
            for (int i = 0; i < 8; ++i) {
                __bf16 b = (__bf16)f[i];
                outv[h][i] = b;
                float bb = (float)b;
                partial += bb * bb;
            }
        }
        int u = col >> 5, c31 = col & 31;
        __bf16* ub = Bp + (size_t)u * USTRIDE;
        *(bf16x8*)(ub + ((size_t)t * 64 + c31) * 8)      = outv[0];
        *(bf16x8*)(ub + ((size_t)t * 64 + 32 + c31) * 8) = outv[1];
        // full-column sum of squares across the 4 sibling lanes
        partial += __shfl_xor(partial, 1);
        partial += __shfl_xor(partial, 2);
        if (t == 0) {
            __bf16 hi = (__bf16)partial;
            __bf16 lo = (__bf16)(partial - (float)hi);
            bf16x8 slot0, zero8;
#pragma unroll
            for (int i = 0; i < 8; ++i) { slot0[i] = (__bf16)0.f; zero8[i] = (__bf16)0.f; }
            slot0[0] = hi; slot0[1] = lo;
            *(bf16x8*)(ub + ((size_t)4 * 64 + c31) * 8)      = slot0;
            *(bf16x8*)(ub + ((size_t)4 * 64 + 32 + c31) * 8) = zero8;
        }
    } else {
        int g = gid - N * 4;
        int row = g >> 2, q = g & 3;
        if (row >= M) return;
        const float* s = pf + (size_t)row * DIM + q * 16;
        float partial = 0.f;
        bf16x8 outv[2];
#pragma unroll
        for (int h = 0; h < 2; ++h) {
            float4 v0 = *(const float4*)(s + h * 8);
            float4 v1 = *(const float4*)(s + h * 8 + 4);
            float f[8] = {v0.x, v0.y, v0.z, v0.w, v1.x, v1.y, v1.z, v1.w};
#pragma unroll
            for (int i = 0; i < 8; ++i) {
                __bf16 b = (__bf16)(f[i] * -2.f);
                outv[h][i] = b;
                float bb = (float)b;
                partial += bb * bb;
            }
        }
        *(bf16x8*)(Ab + (size_t)row * DIM + q * 16)     = outv[0];
        *(bf16x8*)(Ab + (size_t)row * DIM + q * 16 + 8) = outv[1];
        partial += __shfl_xor(partial, 1);
        partial += __shfl_xor(partial, 2);
        if (q == 0) pfsq[row] = partial * 0.25f;
    }
}

// ---------------- main: fused GEMM(K=80) + row-min ----------------
__global__ __launch_bounds__(256, 3)
void igd_main(const __bf16* __restrict__ A, const __bf16* __restrict__ Bp,
              float* __restrict__ partial, int N) {
    const int mTile  = blockIdx.x;
    const int nsplit = blockIdx.y;
    const int lane = threadIdx.x & 63;
    const int wave = threadIdx.x >> 6;
    const int half = lane >> 5;
    const int l31  = lane & 31;
    const int rowBase = mTile * MTILE + wave * 64;

    // ragged split over 32-col units
    const int utotal = N / 32;
    const int ubase  = utotal / NSPLIT;
    const int urem   = utotal % NSPLIT;
    const int ustart = nsplit * ubase + (nsplit < urem ? nsplit : urem);
    const int ucount = ubase + (nsplit < urem ? 1 : 0);

    // Persistent A fragments: lane holds A[row=lane&31][k=half*8+j] per 16-k block
    bf16x8 a[2][4];
#pragma unroll
    for (int g = 0; g < 2; ++g) {
        const __bf16* ap = A + (size_t)(rowBase + 32 * g + l31) * DIM + half * 8;
#pragma unroll
        for (int kf = 0; kf < 4; ++kf)
            a[g][kf] = *(const bf16x8*)(ap + kf * 16);
    }
    // constant 5th A fragment: k=64,65 are 1 (they pick up xsq_hi+xsq_lo from B), rest 0
    bf16x8 a4;
#pragma unroll
    for (int i = 0; i < 8; ++i) a4[i] = (__bf16)0.f;
    if (half == 0) { a4[0] = (__bf16)1.f; a4[1] = (__bf16)1.f; }

    f32x16 zero, m0, m1;   // zero kept loop-invariant -> no per-unit acc zeroing
#pragma unroll
    for (int r = 0; r < 16; ++r) { zero[r] = 0.f; m0[r] = 1e30f; m1[r] = 1e30f; }

    const __bf16* bbase = Bp + (size_t)ustart * USTRIDE + (size_t)lane * 8;

    bf16x8 b0[KF], b1[KF];

#define LOADU(breg, u)                                                         \
    {                                                                          \
        const __bf16* p = bbase + (size_t)(u) * USTRIDE;                       \
        breg[0] = *(const bf16x8*)(p);                                         \
        breg[1] = *(const bf16x8*)(p + 512);                                   \
        breg[2] = *(const bf16x8*)(p + 1024);                                  \
        breg[3] = *(const bf16x8*)(p + 1536);                                  \
        breg[4] = *(const bf16x8*)(p + 2048);                                  \
    }

#define COMPUTE(breg)                                                          \
    {                                                                          \
        f32x16 acc0 = __builtin_amdgcn_mfma_f32_32x32x16_bf16(a[0][0], breg[0], zero, 0, 0, 0); \
        f32x16 acc1 = __builtin_amdgcn_mfma_f32_32x32x16_bf16(a[1][0], breg[0], zero, 0, 0, 0); \
        _Pragma("unroll")                                                      \
        for (int kf = 1; kf < 4; ++kf) {                                       \
            acc0 = __builtin_amdgcn_mfma_f32_32x32x16_bf16(a[0][kf], breg[kf], acc0, 0, 0, 0); \
            acc1 = __builtin_amdgcn_mfma_f32_32x32x16_bf16(a[1][kf], breg[kf], acc1, 0, 0, 0); \
        }                                                                      \
        acc0 = __builtin_amdgcn_mfma_f32_32x32x16_bf16(a4, breg[4], acc0, 0, 0, 0); \
        acc1 = __builtin_amdgcn_mfma_f32_32x32x16_bf16(a4, breg[4], acc1, 0, 0, 0); \
        _Pragma("unroll")                                                      \
        for (int r = 0; r < 16; ++r) {                                         \
            m0[r] = fminf(m0[r], acc0[r]);                                     \
            m1[r] = fminf(m1[r], acc1[r]);                                     \
        }                                                                      \
    }

    LOADU(b0, 0);
    LOADU(b1, 1);
    int u = 0;
    for (; u + 3 < ucount; u += 2) {
        COMPUTE(b0);
        LOADU(b0, u + 2);
        COMPUTE(b1);
        LOADU(b1, u + 3);
    }
    // remaining r = ucount - u is 2 or 3 (ucount >= 42)
    COMPUTE(b0);
    if (u + 2 < ucount) LOADU(b0, u + 2);
    COMPUTE(b1);
    if (u + 2 < ucount) COMPUTE(b0);
#undef LOADU
#undef COMPUTE

    // cross-lane min over the 32 lanes sharing a row
#pragma unroll
    for (int mask = 1; mask <= 16; mask <<= 1) {
#pragma unroll
        for (int r = 0; r < 16; ++r) {
            m0[r] = fminf(m0[r], __shfl_xor(m0[r], mask));
            m1[r] = fminf(m1[r], __shfl_xor(m1[r], mask));
        }
    }
    if (l31 == 0) {
        // C/D layout: row = (r&3) + 8*(r>>2) + 4*half
#pragma unroll
        for (int r = 0; r < 16; ++r) {
            int row0 = rowBase + (r & 3) + 8 * (r >> 2) + 4 * half;
            partial[(size_t)row0 * NSPLIT + nsplit] = m0[r];
            partial[(size_t)(row0 + 32) * NSPLIT + nsplit] = m1[r];
        }
    }
}

// ---------------- reduce: min over splits, add pfsq, sqrt, mean ----------------
__global__ void reduce_kernel(const float* __restrict__ partial, const float* __restrict__ pfsq,
                              float* __restrict__ out, int M, float invM) {
    int row = blockIdx.x * blockDim.x + threadIdx.x;
    float v = 0.f;
    if (row < M) {
        const float* p = partial + (size_t)row * NSPLIT;
        float mn = 3.4e38f;
#pragma unroll
        for (int s = 0; s < NSPLIT; ++s) mn = fminf(mn, p[s]);
        float d2 = mn + pfsq[row];
        v = sqrtf(fmaxf(d2, 0.f)) * invM;
    }
#pragma unroll
    for (int m = 1; m < 64; m <<= 1) v += __shfl_xor(v, m);
    __shared__ float wsum[4];
    int lane = threadIdx.x & 63, w = threadIdx.x >> 6;
    if (lane == 0) wsum[w] = v;
    __syncthreads();
    if (threadIdx.x == 0) atomicAdd(out, wsum[0] + wsum[1] + wsum[2] + wsum[3]);
}

extern "C" void kernel_launch(void* const* d_in, const int* in_sizes, int n_in,
                              void* d_out, int out_size, void* d_ws, size_t ws_size,
                              hipStream_t stream) {
    const float* x  = (const float*)d_in[0];   // [N, 64]
    const float* pf = (const float*)d_in[1];   // [M, 64]
    const int N = in_sizes[0] / DIM;
    const int M = in_sizes[1] / DIM;

    char* ws = (char*)d_ws;
    __bf16* Bp   = (__bf16*)ws;                                       // N*80*2 bytes (packed, K=80)
    __bf16* Ab   = (__bf16*)(ws + (size_t)N * 80 * 2);                // M*64*2 bytes
    float*  pfsq = (float*)(ws + (size_t)N * 80 * 2 + (size_t)M * DIM * 2);
    float*  part = pfsq + M;                                          // M*NSPLIT floats

    int packThreads = (N + M) * 4;
    pack_kernel<<<dim3((packThreads + 255) / 256), 256, 0, stream>>>(
        x, pf, Bp, Ab, pfsq, (float*)d_out, N, M);
    igd_main<<<dim3(M / MTILE, NSPLIT), 256, 0, stream>>>(Ab, Bp, part, N);
    reduce_kernel<<<dim3((M + 255) / 256), 256, 0, stream>>>(part, pfsq, (float*)d_out, M, 1.f / (float)M);
}